// Round 1
// baseline (1270.680 us; speedup 1.0000x reference)
//
#include <hip/hip_runtime.h>
#include <math.h>

#define BGR 64          // graphs
#define N0 512          // nodes/graph at level 1
#define NDEG 16
#define E_TOT (BGR*N0*NDEG)   // 524288 edges, fixed across levels
#define EPG (N0*NDEG)         // 8192 edges per graph at every level
#define HID 128
#define CH 32           // feature chunk for LDS aggregation

static inline int cdiv(int a, int b){ return (a+b-1)/b; }

__global__ void k_fill_f32(float* p, float v, int n){
  int i = blockIdx.x*blockDim.x + threadIdx.x;
  if (i < n) p[i] = v;
}
__global__ void k_fill_i32(int* p, int v, int n){
  int i = blockIdx.x*blockDim.x + threadIdx.x;
  if (i < n) p[i] = v;
}
__global__ void k_edge_init(const int* __restrict__ s0, const int* __restrict__ d0,
                            int* __restrict__ s, int* __restrict__ d, float* __restrict__ m){
  int i = blockIdx.x*blockDim.x + threadIdx.x;
  if (i < E_TOT){ s[i] = s0[i]; d[i] = d0[i]; m[i] = 1.0f; }
}

// h[node, f] = sum_i x[node, i] * W[i, f]   (one block per node, HID threads)
__global__ void k_gemm_node(const float* __restrict__ x, const float* __restrict__ W,
                            float* __restrict__ out, int fin){
  __shared__ float xr[HID];
  int node = blockIdx.x, f = threadIdx.x;
  if (f < fin) xr[f] = x[node*fin + f];
  __syncthreads();
  float acc = 0.f;
  for (int i = 0; i < fin; i++) acc += xr[i]*W[i*HID + f];
  out[node*HID + f] = acc;
}

__global__ void k_deg(const int* __restrict__ dst, const float* __restrict__ em,
                      float* __restrict__ deg){
  int i = blockIdx.x*blockDim.x + threadIdx.x;
  if (i < E_TOT){ float m = em[i]; if (m != 0.f) atomicAdd(&deg[dst[i]], m); }
}
__global__ void k_dinv(const float* __restrict__ deg, float* __restrict__ dinv, int n){
  int i = blockIdx.x*blockDim.x + threadIdx.x;
  if (i < n) dinv[i] = rsqrtf(deg[i]);
}

// Per-(graph, feature-chunk) GCN aggregation in LDS + fused epilogue (self-loop + bias + relu)
// grid = (BGR, HID/CH), block = 256, dyn LDS = nper*CH*4 bytes
__global__ void k_gcn_agg(const float* __restrict__ h, const int* __restrict__ src,
                          const int* __restrict__ dst, const float* __restrict__ em,
                          const float* __restrict__ dinv, const float* __restrict__ bias,
                          float* __restrict__ out, int nper){
  extern __shared__ float lds[];   // nper * CH
  int g = blockIdx.x, c = blockIdx.y;
  int tid = threadIdx.x;
  int lane = tid & (CH-1), sub = tid / CH;       // 256/CH = 8 edge-subgroups
  int nodebase = g*nper, ebase = g*EPG;
  for (int i = tid; i < nper*CH; i += 256) lds[i] = 0.f;
  __syncthreads();
  for (int e = sub; e < EPG; e += 256/CH){
    float m = em[ebase + e];
    if (m != 0.f){
      int s = src[ebase + e], d = dst[ebase + e];
      float coeff = dinv[s]*dinv[d]*m;
      atomicAdd(&lds[(d - nodebase)*CH + lane], h[s*HID + c*CH + lane]*coeff);
    }
  }
  __syncthreads();
  for (int ln = sub; ln < nper; ln += 256/CH){
    int node = nodebase + ln, f = c*CH + lane;
    float di = dinv[node];
    float v = lds[ln*CH + lane] + h[node*HID + f]*di*di + bias[f];
    out[node*HID + f] = fmaxf(v, 0.f);
  }
}

// hp[i] = dot(x[i,:], Wp)  (score GCN's XW, HID -> 1)
__global__ void k_hp(const float* __restrict__ x, const float* __restrict__ Wp,
                     float* __restrict__ hp, int n){
  int i = blockIdx.x*blockDim.x + threadIdx.x;
  if (i < n){
    float a = 0.f;
    #pragma unroll
    for (int f = 0; f < HID; f++) a += x[i*HID + f]*Wp[f];
    hp[i] = a;
  }
}

// score = tanh(agg_p + hp*dinv^2 + bp), per-graph LDS accumulation (F=1)
__global__ void k_score(const float* __restrict__ hp, const int* __restrict__ src,
                        const int* __restrict__ dst, const float* __restrict__ em,
                        const float* __restrict__ dinv, const float* __restrict__ bp,
                        float* __restrict__ score, int nper){
  extern __shared__ float lds[];   // nper
  int g = blockIdx.x, tid = threadIdx.x;
  int nodebase = g*nper, ebase = g*EPG;
  for (int i = tid; i < nper; i += 256) lds[i] = 0.f;
  __syncthreads();
  for (int e = tid; e < EPG; e += 256){
    float m = em[ebase + e];
    if (m != 0.f){
      int s = src[ebase + e], d = dst[ebase + e];
      atomicAdd(&lds[d - nodebase], hp[s]*dinv[s]*dinv[d]*m);
    }
  }
  __syncthreads();
  for (int ln = tid; ln < nper; ln += 256){
    int node = nodebase + ln;
    float di = dinv[node];
    score[node] = tanhf(lds[ln] + hp[node]*di*di + bp[0]);
  }
}

// Per-graph bitonic top-k (descending, ties -> lower index like jax top_k),
// then write pooled features x[perm]*val and mapping[perm]=new_id.
__global__ void k_topk(const float* __restrict__ score, const float* __restrict__ x,
                       float* __restrict__ xnew, int* __restrict__ mapping, int nper){
  __shared__ float sv[512];
  __shared__ int   si[512];
  int g = blockIdx.x, tid = threadIdx.x;
  int k = nper >> 1;
  for (int j = tid; j < nper; j += 256){ sv[j] = score[g*nper + j]; si[j] = j; }
  __syncthreads();
  for (int kk = 2; kk <= nper; kk <<= 1){
    for (int jj = kk >> 1; jj > 0; jj >>= 1){
      for (int i = tid; i < nper; i += 256){
        int ixj = i ^ jj;
        if (ixj > i){
          float av = sv[i], bv = sv[ixj];
          int   ai = si[i], bi = si[ixj];
          // "a comes after b" in desired order (desc by value, ties: lower idx first)
          bool worseA = (av < bv) || (av == bv && ai > bi);
          bool dir = ((i & kk) == 0);
          bool sw = dir ? worseA : !worseA;
          if (sw){ sv[i] = bv; si[i] = bi; sv[ixj] = av; si[ixj] = ai; }
        }
      }
      __syncthreads();
    }
  }
  for (int t = tid; t < k*HID; t += 256){
    int j = t >> 7, f = t & (HID-1);
    xnew[(g*k + j)*HID + f] = x[(g*nper + si[j])*HID + f] * sv[j];
  }
  for (int j = tid; j < k; j += 256) mapping[g*nper + si[j]] = g*k + j;
}

__global__ void k_relabel(int* __restrict__ src, int* __restrict__ dst,
                          float* __restrict__ em, const int* __restrict__ mapping){
  int i = blockIdx.x*blockDim.x + threadIdx.x;
  if (i < E_TOT){
    int s = src[i], d = dst[i];
    float m = em[i];
    int ns = mapping[s], nd = mapping[d];
    bool ok = (m != 0.f) && (ns >= 0) && (nd >= 0);
    src[i] = ok ? ns : 0;
    dst[i] = ok ? nd : 0;
    em[i]  = ok ? 1.f : 0.f;
  }
}

// z[g, 0:128] += max over k nodes; z[g, 128:256] += mean
__global__ void k_readout(const float* __restrict__ xp, float* __restrict__ z, int k){
  int g = blockIdx.x, f = threadIdx.x;   // 128 threads
  float mx = -INFINITY, sm = 0.f;
  for (int j = 0; j < k; j++){
    float v = xp[(g*k + j)*HID + f];
    mx = fmaxf(mx, v); sm += v;
  }
  z[g*256 + f]       += mx;
  z[g*256 + 128 + f] += sm / (float)k;
}

// z(64x256) -> relu(@L1W+b) -> relu(@L2W+b) -> log_softmax. One block per graph.
__global__ void k_mlp(const float* __restrict__ z, const float* __restrict__ L1W,
                      const float* __restrict__ L1b, const float* __restrict__ L2W,
                      const float* __restrict__ L2b, float* __restrict__ out){
  __shared__ float zr[256];
  __shared__ float h1[128];
  __shared__ float h2[64];
  __shared__ float red[2];
  int g = blockIdx.x, t = threadIdx.x;
  zr[t] = z[g*256 + t];
  __syncthreads();
  if (t < 128){
    float a = L1b[t];
    for (int i = 0; i < 256; i++) a += zr[i]*L1W[i*128 + t];
    h1[t] = fmaxf(a, 0.f);
  }
  __syncthreads();
  if (t < 64){
    float a = L2b[t];
    for (int i = 0; i < 128; i++) a += h1[i]*L2W[i*64 + t];
    h2[t] = fmaxf(a, 0.f);
  }
  __syncthreads();
  if (t == 0){
    float mx = -INFINITY;
    for (int i = 0; i < 64; i++) mx = fmaxf(mx, h2[i]);
    float s = 0.f;
    for (int i = 0; i < 64; i++) s += expf(h2[i] - mx);
    red[0] = mx; red[1] = logf(s);
  }
  __syncthreads();
  if (t < 64) out[g*64 + t] = h2[t] - red[0] - red[1];
}

static void run_level(const float* xin, int fin, const float* W, const float* b,
                      const float* Wp, const float* bp, int nper,
                      int* srcc, int* dstc, float* emk,
                      float* h, float* gout, float* deg, float* dinvv,
                      float* hp, float* score, int* mapping,
                      float* xpool, float* z, bool do_relabel, hipStream_t stream){
  int n = BGR*nper, k = nper/2;
  k_gemm_node<<<n, HID, 0, stream>>>(xin, W, h, fin);
  k_fill_f32<<<cdiv(n,256), 256, 0, stream>>>(deg, 1.0f, n);      // +1 self-loop
  k_deg<<<cdiv(E_TOT,256), 256, 0, stream>>>(dstc, emk, deg);
  k_dinv<<<cdiv(n,256), 256, 0, stream>>>(deg, dinvv, n);
  k_gcn_agg<<<dim3(BGR, HID/CH), 256, nper*CH*4, stream>>>(h, srcc, dstc, emk, dinvv, b, gout, nper);
  k_hp<<<cdiv(n,256), 256, 0, stream>>>(gout, Wp, hp, n);
  k_score<<<BGR, 256, nper*4, stream>>>(hp, srcc, dstc, emk, dinvv, bp, score, nper);
  k_fill_i32<<<cdiv(n,256), 256, 0, stream>>>(mapping, -1, n);
  k_topk<<<BGR, 256, 0, stream>>>(score, gout, xpool, mapping, nper);
  if (do_relabel) k_relabel<<<cdiv(E_TOT,256), 256, 0, stream>>>(srcc, dstc, emk, mapping);
  k_readout<<<BGR, HID, 0, stream>>>(xpool, z, k);
}

extern "C" void kernel_launch(void* const* d_in, const int* in_sizes, int n_in,
                              void* d_out, int out_size, void* d_ws, size_t ws_size,
                              hipStream_t stream){
  (void)in_sizes; (void)n_in; (void)out_size; (void)ws_size;
  const float* x0  = (const float*)d_in[0];
  const int*   s0  = (const int*)  d_in[1];
  const int*   d0  = (const int*)  d_in[2];
  const float* W1  = (const float*)d_in[3];  const float* b1 = (const float*)d_in[4];
  const float* W2  = (const float*)d_in[5];  const float* b2 = (const float*)d_in[6];
  const float* W3  = (const float*)d_in[7];  const float* b3 = (const float*)d_in[8];
  const float* Wp  = (const float*)d_in[9];  const float* bp = (const float*)d_in[10];
  const float* L1W = (const float*)d_in[11]; const float* L1b = (const float*)d_in[12];
  const float* L2W = (const float*)d_in[13]; const float* L2b = (const float*)d_in[14];
  float* out = (float*)d_out;

  // workspace layout (fp32 elements)
  float* w = (float*)d_ws;
  float* h     = w; w += 32768*HID;          // XW scratch (max level-1 size)
  float* gout  = w; w += 32768*HID;          // GCN output
  float* xpA   = w; w += 16384*HID;          // pool-1 output / pool-3 output
  float* xpB   = w; w += 8192*HID;           // pool-2 output
  float* deg   = w; w += 32768;
  float* dinvv = w; w += 32768;
  float* hp    = w; w += 32768;
  float* score = w; w += 32768;
  float* emk   = w; w += E_TOT;
  float* z     = w; w += BGR*256;
  int* mapping = (int*)w; w += 32768;
  int* srcc    = (int*)w; w += E_TOT;
  int* dstc    = (int*)w; w += E_TOT;

  k_edge_init<<<cdiv(E_TOT,256), 256, 0, stream>>>(s0, d0, srcc, dstc, emk);
  k_fill_f32<<<cdiv(BGR*256,256), 256, 0, stream>>>(z, 0.f, BGR*256);

  // level 1: 512 nodes/graph -> 256
  run_level(x0, 10, W1, b1, Wp, bp, 512, srcc, dstc, emk,
            h, gout, deg, dinvv, hp, score, mapping, xpA, z, true, stream);
  // level 2: 256 -> 128
  run_level(xpA, HID, W2, b2, Wp, bp, 256, srcc, dstc, emk,
            h, gout, deg, dinvv, hp, score, mapping, xpB, z, true, stream);
  // level 3: 128 -> 64 (no relabel needed after final pool)
  run_level(xpB, HID, W3, b3, Wp, bp, 128, srcc, dstc, emk,
            h, gout, deg, dinvv, hp, score, mapping, xpA, z, false, stream);

  k_mlp<<<BGR, 256, 0, stream>>>(z, L1W, L1b, L2W, L2b, out);
}

// Round 2
// 477.319 us; speedup vs baseline: 2.6621x; 2.6621x over previous
//
#include <hip/hip_runtime.h>
#include <math.h>

#define BGR 64          // graphs
#define N0 512          // nodes/graph at level 1
#define NDEG 16
#define E_TOT (BGR*N0*NDEG)   // 524288 edge slots, fixed across levels
#define EPG (N0*NDEG)         // 8192 edge slots per graph at every level
#define HID 128

static inline int cdiv(int a, int b){ return (a+b-1)/b; }

__global__ void k_fill_f32(float* p, float v, int n){
  int i = blockIdx.x*blockDim.x + threadIdx.x;
  if (i < n) p[i] = v;
}
__global__ void k_fill_i32(int* p, int v, int n){
  int i = blockIdx.x*blockDim.x + threadIdx.x;
  if (i < n) p[i] = v;
}
// copy edges; src = -1 marks dead edges in later levels
__global__ void k_edge_init(const int* __restrict__ s0, const int* __restrict__ d0,
                            int* __restrict__ s, int* __restrict__ d){
  int i = blockIdx.x*blockDim.x + threadIdx.x;
  if (i < E_TOT){ s[i] = s0[i]; d[i] = d0[i]; }
}

// h = x @ W, 8 nodes per 128-thread block (reuse W across nodes)
__global__ void k_gemm8(const float* __restrict__ x, const float* __restrict__ W,
                        float* __restrict__ out, int fin){
  __shared__ float xr[8][HID];
  int base = blockIdx.x*8, f = threadIdx.x;
  #pragma unroll
  for (int nd = 0; nd < 8; nd++) if (f < fin) xr[nd][f] = x[(base+nd)*fin + f];
  __syncthreads();
  float acc[8] = {0,0,0,0,0,0,0,0};
  for (int i = 0; i < fin; i++){
    float wv = W[i*HID + f];
    #pragma unroll
    for (int nd = 0; nd < 8; nd++) acc[nd] += xr[nd][i]*wv;
  }
  #pragma unroll
  for (int nd = 0; nd < 8; nd++) out[(base+nd)*HID + f] = acc[nd];
}

__global__ void k_deg_cnt(const int* __restrict__ src, const int* __restrict__ dst,
                          int* __restrict__ cnt){
  int i = blockIdx.x*blockDim.x + threadIdx.x;
  if (i < E_TOT){ int s = src[i]; if (s >= 0) atomicAdd(&cnt[dst[i]], 1); }
}
__global__ void k_dinv(const int* __restrict__ cnt, float* __restrict__ dinv, int n){
  int i = blockIdx.x*blockDim.x + threadIdx.x;
  if (i < n) dinv[i] = rsqrtf((float)cnt[i] + 1.0f);   // +1 self-loop
}

// per-graph exclusive scan of cnt -> rowptr & cursor (CSR slots at g*EPG+offset)
__global__ void k_scan(const int* __restrict__ cnt, int* __restrict__ rowptr,
                       int* __restrict__ cursor, int nper){
  __shared__ int sb[512];
  int g = blockIdx.x, t = threadIdx.x;
  int v = (t < nper) ? cnt[g*nper + t] : 0;
  sb[t] = v; __syncthreads();
  for (int off = 1; off < nper; off <<= 1){
    int add = (t >= off) ? sb[t-off] : 0;
    __syncthreads();
    sb[t] += add;
    __syncthreads();
  }
  if (t < nper){
    int excl = sb[t] - v;
    rowptr[g*nper + t] = g*EPG + excl;
    cursor[g*nper + t] = g*EPG + excl;
  }
}

// pack each live edge as {src, bitcast(dinv[s]*dinv[d])} into dst's CSR row
__global__ void k_csr_fill(const int* __restrict__ src, const int* __restrict__ dst,
                           const float* __restrict__ dinv, int* __restrict__ cursor,
                           int2* __restrict__ csr){
  int i = blockIdx.x*blockDim.x + threadIdx.x;
  if (i < E_TOT){
    int s = src[i];
    if (s >= 0){
      int d = dst[i];
      int pos = atomicAdd(&cursor[d], 1);
      csr[pos] = make_int2(s, __float_as_int(dinv[s]*dinv[d]));
    }
  }
}

// gather GCN: 2 nodes x 128 feats per block; fused self-loop+bias+relu and hp=row.Wp
__global__ __launch_bounds__(256) void k_gcn_gather(
    const float* __restrict__ h, const int2* __restrict__ csr,
    const int* __restrict__ rowptr, const int* __restrict__ cnt,
    const float* __restrict__ dinv, const float* __restrict__ bias,
    const float* __restrict__ Wp, float* __restrict__ out, float* __restrict__ hp){
  __shared__ float hpart[4];
  int tid = threadIdx.x;
  int sub = tid >> 7, f = tid & 127;
  int node = blockIdx.x*2 + sub;
  int start = rowptr[node], c = cnt[node];
  float acc = 0.f;
  if (c > 0){
    int2 e = csr[start];
    for (int j = 1; j < c; j++){
      int2 en = csr[start + j];
      acc += __int_as_float(e.y) * h[e.x*HID + f];
      e = en;
    }
    acc += __int_as_float(e.y) * h[e.x*HID + f];
  }
  float di = dinv[node];
  float v = acc + h[node*HID + f]*di*di + bias[f];
  v = fmaxf(v, 0.f);
  out[node*HID + f] = v;
  // hp[node] = dot(out_row, Wp)
  float contrib = v * Wp[f];
  #pragma unroll
  for (int off = 32; off; off >>= 1) contrib += __shfl_down(contrib, off, 64);
  if ((tid & 63) == 0) hpart[tid >> 6] = contrib;
  __syncthreads();
  if (f == 0) hp[node] = hpart[sub*2] + hpart[sub*2 + 1];
}

// per-graph: score (CSR gather over hp) -> bitonic top-k -> pooled features,
// mapping, and fused max/mean readout accumulation into z
__global__ void k_pool(const float* __restrict__ gout, const float* __restrict__ hp,
                       const int2* __restrict__ csr, const int* __restrict__ rowptr,
                       const int* __restrict__ cnt, const float* __restrict__ dinv,
                       const float* __restrict__ bp, float* __restrict__ xpool,
                       int* __restrict__ mapping, float* __restrict__ z, int nper){
  __shared__ float sv[512];
  __shared__ int   si[512];
  __shared__ float redmx[2][128];
  __shared__ float redsm[2][128];
  int g = blockIdx.x, tid = threadIdx.x;
  int k = nper >> 1, gbase = g*nper;
  for (int ln = tid; ln < nper; ln += 256){
    int node = gbase + ln;
    int start = rowptr[node], c = cnt[node];
    float a = 0.f;
    for (int j = 0; j < c; j++){
      int2 e = csr[start + j];
      a += __int_as_float(e.y) * hp[e.x];
    }
    float di = dinv[node];
    sv[ln] = tanhf(a + hp[node]*di*di + bp[0]);
    si[ln] = ln;
    mapping[node] = -1;
  }
  __syncthreads();
  // bitonic sort desc by value, ties -> lower index first (matches jax top_k)
  for (int kk = 2; kk <= nper; kk <<= 1){
    for (int jj = kk >> 1; jj > 0; jj >>= 1){
      for (int i = tid; i < nper; i += 256){
        int ixj = i ^ jj;
        if (ixj > i){
          float av = sv[i], bv = sv[ixj];
          int   ai = si[i], bi = si[ixj];
          bool worseA = (av < bv) || (av == bv && ai > bi);
          bool dir = ((i & kk) == 0);
          bool sw = dir ? worseA : !worseA;
          if (sw){ sv[i] = bv; si[i] = bi; sv[ixj] = av; si[ixj] = ai; }
        }
      }
      __syncthreads();
    }
  }
  // pooled features + readout partials
  int f = tid & 127, jh = tid >> 7;
  float mx = -INFINITY, sm = 0.f;
  for (int j = jh; j < k; j += 2){
    float v = gout[(gbase + si[j])*HID + f] * sv[j];
    xpool[(g*k + j)*HID + f] = v;
    mx = fmaxf(mx, v); sm += v;
  }
  redmx[jh][f] = mx; redsm[jh][f] = sm;
  __syncthreads();
  if (jh == 0){
    z[g*256 + f]       += fmaxf(redmx[0][f], redmx[1][f]);
    z[g*256 + 128 + f] += (redsm[0][f] + redsm[1][f]) / (float)k;
  }
  for (int j = tid; j < k; j += 256) mapping[gbase + si[j]] = g*k + j;
}

__global__ void k_relabel(int* __restrict__ src, int* __restrict__ dst,
                          const int* __restrict__ mapping){
  int i = blockIdx.x*blockDim.x + threadIdx.x;
  if (i < E_TOT){
    int s = src[i];
    if (s < 0) return;
    int ns = mapping[s], nd = mapping[dst[i]];
    if (ns < 0 || nd < 0){ src[i] = -1; }
    else { src[i] = ns; dst[i] = nd; }
  }
}

// z(64x256) -> relu(@L1W+b) -> relu(@L2W+b) -> log_softmax. One block per graph.
__global__ void k_mlp(const float* __restrict__ z, const float* __restrict__ L1W,
                      const float* __restrict__ L1b, const float* __restrict__ L2W,
                      const float* __restrict__ L2b, float* __restrict__ out){
  __shared__ float zr[256];
  __shared__ float h1[128];
  __shared__ float h2[64];
  __shared__ float red[2];
  int g = blockIdx.x, t = threadIdx.x;
  zr[t] = z[g*256 + t];
  __syncthreads();
  if (t < 128){
    float a = L1b[t];
    for (int i = 0; i < 256; i++) a += zr[i]*L1W[i*128 + t];
    h1[t] = fmaxf(a, 0.f);
  }
  __syncthreads();
  if (t < 64){
    float a = L2b[t];
    for (int i = 0; i < 128; i++) a += h1[i]*L2W[i*64 + t];
    h2[t] = fmaxf(a, 0.f);
  }
  __syncthreads();
  if (t == 0){
    float mx = -INFINITY;
    for (int i = 0; i < 64; i++) mx = fmaxf(mx, h2[i]);
    float s = 0.f;
    for (int i = 0; i < 64; i++) s += expf(h2[i] - mx);
    red[0] = mx; red[1] = logf(s);
  }
  __syncthreads();
  if (t < 64) out[g*64 + t] = h2[t] - red[0] - red[1];
}

static void run_level(const float* xin, int fin, const float* W, const float* b,
                      const float* Wp, const float* bp, int nper,
                      int* srcc, int* dstc, int2* csr, int* rowptr, int* cursmap,
                      int* cnt, float* dinvv, float* hp,
                      float* h, float* gout, float* xpool, float* z,
                      bool do_relabel, hipStream_t stream){
  int n = BGR*nper;
  k_gemm8<<<n/8, HID, 0, stream>>>(xin, W, h, fin);
  k_fill_i32<<<cdiv(n,256), 256, 0, stream>>>(cnt, 0, n);
  k_deg_cnt<<<cdiv(E_TOT,256), 256, 0, stream>>>(srcc, dstc, cnt);
  k_dinv<<<cdiv(n,256), 256, 0, stream>>>(cnt, dinvv, n);
  k_scan<<<BGR, 512, 0, stream>>>(cnt, rowptr, cursmap, nper);
  k_csr_fill<<<cdiv(E_TOT,256), 256, 0, stream>>>(srcc, dstc, dinvv, cursmap, csr);
  k_gcn_gather<<<n/2, 256, 0, stream>>>(h, csr, rowptr, cnt, dinvv, b, Wp, gout, hp);
  k_pool<<<BGR, 256, 0, stream>>>(gout, hp, csr, rowptr, cnt, dinvv, bp,
                                  xpool, cursmap, z, nper);
  if (do_relabel) k_relabel<<<cdiv(E_TOT,256), 256, 0, stream>>>(srcc, dstc, cursmap);
}

extern "C" void kernel_launch(void* const* d_in, const int* in_sizes, int n_in,
                              void* d_out, int out_size, void* d_ws, size_t ws_size,
                              hipStream_t stream){
  (void)in_sizes; (void)n_in; (void)out_size; (void)ws_size;
  const float* x0  = (const float*)d_in[0];
  const int*   s0  = (const int*)  d_in[1];
  const int*   d0  = (const int*)  d_in[2];
  const float* W1  = (const float*)d_in[3];  const float* b1 = (const float*)d_in[4];
  const float* W2  = (const float*)d_in[5];  const float* b2 = (const float*)d_in[6];
  const float* W3  = (const float*)d_in[7];  const float* b3 = (const float*)d_in[8];
  const float* Wp  = (const float*)d_in[9];  const float* bp = (const float*)d_in[10];
  const float* L1W = (const float*)d_in[11]; const float* L1b = (const float*)d_in[12];
  const float* L2W = (const float*)d_in[13]; const float* L2b = (const float*)d_in[14];
  float* out = (float*)d_out;

  // workspace layout (elements). xp buffers overlay the dead tails of h/gout.
  float* w = (float*)d_ws;
  float* h     = w; w += 32768*HID;          // level XW scratch (level L uses first n*HID)
  float* gout  = w; w += 32768*HID;          // GCN output
  float* xpA   = h    + 16384*HID;           // level-1 pool out (16384x128) — h tail
  float* xpB   = gout + 16384*HID;           // level-2 pool out (8192x128) — gout tail
  float* xpC   = xpA;                        // level-3 pool out (8192x128) — xpA dead
  float* dinvv = w; w += 32768;
  float* hp    = w; w += 32768;
  float* z     = w; w += BGR*256;
  int* cnt     = (int*)w; w += 32768;
  int* rowptr  = (int*)w; w += 32768;
  int* cursmap = (int*)w; w += 32768;        // shared: CSR cursor (early) / mapping (late)
  int* srcc    = (int*)w; w += E_TOT;
  int* dstc    = (int*)w; w += E_TOT;
  int2* csr    = (int2*)w; w += E_TOT*2;

  k_edge_init<<<cdiv(E_TOT,256), 256, 0, stream>>>(s0, d0, srcc, dstc);
  k_fill_f32<<<cdiv(BGR*256,256), 256, 0, stream>>>(z, 0.f, BGR*256);

  // level 1: 512 nodes/graph -> 256
  run_level(x0, 10, W1, b1, Wp, bp, 512, srcc, dstc, csr, rowptr, cursmap,
            cnt, dinvv, hp, h, gout, xpA, z, true, stream);
  // level 2: 256 -> 128
  run_level(xpA, HID, W2, b2, Wp, bp, 256, srcc, dstc, csr, rowptr, cursmap,
            cnt, dinvv, hp, h, gout, xpB, z, true, stream);
  // level 3: 128 -> 64 (no relabel after final pool)
  run_level(xpB, HID, W3, b3, Wp, bp, 128, srcc, dstc, csr, rowptr, cursmap,
            cnt, dinvv, hp, h, gout, xpC, z, false, stream);

  k_mlp<<<BGR, 256, 0, stream>>>(z, L1W, L1b, L2W, L2b, out);
}